// Round 5
// baseline (140.528 us; speedup 1.0000x reference)
//
#include <hip/hip_runtime.h>

#ifndef __has_builtin
#define __has_builtin(x) 0
#endif

#if __has_builtin(__builtin_amdgcn_exp2f)
#define EXP2F(x) __builtin_amdgcn_exp2f(x)
#else
#define EXP2F(x) exp2f(x)
#endif

#if __has_builtin(__builtin_amdgcn_rcpf)
#define RCPF(x) __builtin_amdgcn_rcpf(x)
#else
#define RCPF(x) (1.0f / (x))
#endif

#define LOG2E_F 1.4426950408889634f

// nck exp-arg constants, exp(a) = exp2(a*log2e) folded (bit-exact vs ref, R2):
#define CA1 (-0.16065646437f)
#define CA0 ( 9.2188213109f)
#define CB1 (-0.33945766845f)
#define CB0 (-6.3478581799f)
#define CC1 (-0.19043574540f)
#define CC0 ( 3.1878943779f)

struct TreeParams {
  const float* w[9];
  const float* b[9];
};

__device__ __forceinline__ float nck_eval(float z, float A1, float A0,
                                          float B1, float B0, float G) {
  float ea = EXP2F(fmaf(z, CA1, CA0));
  float eb = EXP2F(fmaf(z, CB1, CB0));
  float ec = EXP2F(fmaf(z, CC1, CC0));
  float ra = RCPF(1.0f + ea);
  float rb = RCPF(1.0f + eb);
  float rc = RCPF(0.436f + ec);
  return fmaf(fmaf(z, A1, A0), ra, fmaf(fmaf(z, B1, B0), rb, G * rc));
}

// Wiring (verified bit-exact R2/R3):
//   V_8[k] = nck(x[:,255-k]*w0[k] + b0[255+k])
//   merge at parent depth d, k = pre_d ^ (0x55 & ((1<<d)-1)):
//     z = w[2k]*(first DFS child) + w[2k+1]*(second) + bc[2^d-1+k],
//     wo(d) = 768 - 2^(d+2)
//   leaf at DFS pos ig: k8 = ig^0x55, x col = ig^0xAA
// R4 mapping: block = 1024 thr = 16 waves; wave w = depth-4 DFS prefix
// (16-leaf subtree), lane e = element. 8192 waves total = 8 waves/SIMD
// (R3 had 4). x = 4 float4/lane in regs; DFS stack in regs (constexpr
// indices); top 4 levels (15 ncks) combined on wave 0 via small LDS.

template <int I>
__device__ __forceinline__ float xget(const float4* xr) {
  constexpr int q = I >> 2, r = I & 3;
  if constexpr (r == 0) return xr[q].x;
  else if constexpr (r == 1) return xr[q].y;
  else if constexpr (r == 2) return xr[q].z;
  else return xr[q].w;
}

struct Ctx {
  const float4* xr;   // 4 float4 = lane's 16 x values (cols base..base+15)
  const float* wc;    // LDS concat weights (766)
  const float* bc;    // LDS biases by node id (511)
  int w;              // wave id 0..15 (= pre4)
  float A1, A0, B1, B0, G;
};

template <int D, int CPRE>
__device__ __forceinline__ float node_eval(const Ctx& c) {
  if constexpr (D == 8) {
    constexpr int t = CPRE;                        // local leaf 0..15
    const int k8 = ((c.w ^ 5) << 4) | (t ^ 5);     // ((w<<4)|t) ^ 0x55
    const float xv = xget<(t ^ 0x0A)>(c.xr);       // col low nibble = t^0xA
    return nck_eval(fmaf(xv, c.wc[k8], c.bc[255 + k8]),
                    c.A1, c.A0, c.B1, c.B0, c.G);
  } else {
    const float a = node_eval<D + 1, 2 * CPRE>(c);      // first DFS child
    const float b = node_eval<D + 1, 2 * CPRE + 1>(c);  // second
    const int k = ((c.w << (D - 4)) | CPRE) ^ (0x55 & ((1 << D) - 1));
    constexpr int wo = 768 - (1 << (D + 2));
    const float z = fmaf(c.wc[wo + 2 * k], a,
                         fmaf(c.wc[wo + 2 * k + 1], b,
                              c.bc[(1 << D) - 1 + k]));
    return nck_eval(z, c.A1, c.A0, c.B1, c.B0, c.G);
  }
}

__global__ __launch_bounds__(1024, 8)
void asym_tree_fwd(const float* __restrict__ x, TreeParams p,
                   const float* __restrict__ alpha_p,
                   const float* __restrict__ beta_p,
                   const float* __restrict__ gamma_p,
                   const float* __restrict__ rw_p,
                   const float* __restrict__ rb_p,
                   float* __restrict__ out) {
  __shared__ float wc[766];      // w0..w8 @ 0,256,512,640,704,736,752,760,764
  __shared__ float bc[511];      // bias per node id
  __shared__ float v4[16][64];   // depth-4 results; uniform-row reads -> 2-way

  const int tid = threadIdx.x;
  const int e = tid & 63;        // element (lane)
  const int w = tid >> 6;        // wave = depth-4 DFS prefix

  // ---- issue x loads first; lane e needs cols [((w^0xA)<<4), +16) ----
  const float4* xsrc = reinterpret_cast<const float4*>(
      x + (((size_t)blockIdx.x * 64 + e) * 256 + ((w ^ 0xA) << 4)));
  float4 xr[4];
#pragma unroll
  for (int i = 0; i < 4; ++i) xr[i] = xsrc[i];

  // ---- stage weights + biases to LDS ----
  {
    const int wsz[9] = {256, 256, 128, 64, 32, 16, 8, 4, 2};
    int off = 0;
#pragma unroll
    for (int l = 0; l < 9; ++l) {
      if (tid < wsz[l]) wc[off + tid] = p.w[l][tid];
      off += wsz[l];
    }
#pragma unroll
    for (int l = 0; l < 9; ++l) {
      int d = 8 - l;
      int base = (1 << d) - 1;
      int cnt = 1 << d;
      if (tid < cnt) bc[base + tid] = p.b[l][base + tid];
    }
  }
  __syncthreads();

  const float alpha = alpha_p[0], beta = beta_p[0], gamma = gamma_p[0];
  Ctx c;
  c.xr = xr; c.wc = wc; c.bc = bc; c.w = w;
  c.A1 = alpha * 0.0878f; c.A0 = -c.A1 * 113.68f;
  c.B1 = beta * 0.129f;   c.B0 = -c.B1 * 69.62f;
  c.G  = gamma * 2.23f;

  // ---- fully-unrolled register DFS: depth-4 subtree (16 leaves, 31 ncks) --
  v4[w][e] = node_eval<4, 0>(c);
  __syncthreads();

  // ---- top 4 levels (8+4+2+1 ncks) + sigmoid on wave 0 ----
  if (w == 0) {
    float v3[8];
#pragma unroll
    for (int q = 0; q < 8; ++q) {   // depth-3: k3 = q^5, wo=736, bc[7+k3]
      const int k3 = q ^ 5;
      v3[q] = nck_eval(fmaf(wc[736 + 2 * k3], v4[2 * q][e],
                            fmaf(wc[737 + 2 * k3], v4[2 * q + 1][e],
                                 bc[7 + k3])),
                       c.A1, c.A0, c.B1, c.B0, c.G);
    }
    float v2[4];
#pragma unroll
    for (int q = 0; q < 4; ++q) {   // depth-2: k2 = q^1, wo=752, bc[3+k2]
      const int k2 = q ^ 1;
      v2[q] = nck_eval(fmaf(wc[752 + 2 * k2], v3[2 * q],
                            fmaf(wc[753 + 2 * k2], v3[2 * q + 1], bc[3 + k2])),
                       c.A1, c.A0, c.B1, c.B0, c.G);
    }
    float v1[2];
#pragma unroll
    for (int q = 0; q < 2; ++q) {   // depth-1: k1 = q^1, wo=760, bc[1+k1]
      const int k1 = q ^ 1;
      v1[q] = nck_eval(fmaf(wc[760 + 2 * k1], v2[2 * q],
                            fmaf(wc[761 + 2 * k1], v2[2 * q + 1], bc[1 + k1])),
                       c.A1, c.A0, c.B1, c.B0, c.G);
    }
    // root: wo=764, k=0
    const float y = nck_eval(fmaf(wc[764], v1[0], fmaf(wc[765], v1[1], bc[0])),
                             c.A1, c.A0, c.B1, c.B0, c.G);
    const float o = fmaf(rw_p[0], y, rb_p[0]);
    out[(size_t)blockIdx.x * 64 + e] = RCPF(1.0f + EXP2F(-o * LOG2E_F));
  }
}

extern "C" void kernel_launch(void* const* d_in, const int* in_sizes, int n_in,
                              void* d_out, int out_size, void* d_ws,
                              size_t ws_size, hipStream_t stream) {
  (void)n_in; (void)d_ws; (void)ws_size; (void)out_size;
  const float* x = (const float*)d_in[0];
  TreeParams p;
  for (int l = 0; l < 9; ++l) {
    p.w[l] = (const float*)d_in[1 + 2 * l];
    p.b[l] = (const float*)d_in[2 + 2 * l];
  }
  const float* alpha = (const float*)d_in[19];
  const float* beta  = (const float*)d_in[20];
  const float* gamma = (const float*)d_in[21];
  const float* rw    = (const float*)d_in[22];
  const float* rb    = (const float*)d_in[23];
  float* out = (float*)d_out;

  const int batch = in_sizes[0] / 256;   // 32768
  const int grid = batch / 64;           // 512 blocks x 1024 threads (16 waves)
  asym_tree_fwd<<<grid, 1024, 0, stream>>>(x, p, alpha, beta, gamma, rw, rb,
                                           out);
}